// Round 11
// baseline (1264.424 us; speedup 1.0000x reference)
//
#include <hip/hip_runtime.h>
#include <math.h>

#define NT 64
#define KN 48
#define RPB 24          // neighbor rows per block
#define TOBS 30
#define NPRED 15
#define EMB 64
#define NODE 128
#define EDGE 256
#define ATTD 64
#define CNN 512
#define GNN 1024
#define GTT 512
#define KKA 320
#define TMAX 44

typedef _Float16 f16;
typedef f16 f16x8 __attribute__((ext_vector_type(8)));
typedef f16 f16x2 __attribute__((ext_vector_type(2)));
typedef float f32x4 __attribute__((ext_vector_type(4)));

__device__ __forceinline__ float rcp_f(float x) { return __builtin_amdgcn_rcpf(x); }
__device__ __forceinline__ float sigm(float x) { return rcp_f(1.f + __expf(-x)); }
__device__ __forceinline__ float tanh_f(float x) {
  float xx = fminf(fmaxf(x, -20.f), 20.f);
  float e = __expf(-2.f * xx);
  return (1.f - e) * rcp_f(1.f + e);
}
__device__ __forceinline__ unsigned ldcoh(const unsigned* p) {
  return __hip_atomic_load(p, __ATOMIC_RELAXED, __HIP_MEMORY_SCOPE_AGENT);
}
__device__ __forceinline__ float ldcohf(const float* p) {
  unsigned u = __hip_atomic_load((const unsigned*)p, __ATOMIC_RELAXED, __HIP_MEMORY_SCOPE_AGENT);
  return __builtin_bit_cast(float, u);
}
__device__ __forceinline__ void stcoh(unsigned* p, unsigned v) {
  __hip_atomic_store(p, v, __ATOMIC_RELAXED, __HIP_MEMORY_SCOPE_AGENT);
}
__device__ __forceinline__ void stcohf(float* p, float v) {
  __hip_atomic_store((unsigned*)p, __builtin_bit_cast(unsigned, v),
                     __ATOMIC_RELAXED, __HIP_MEMORY_SCOPE_AGENT);
}

// ---------------- prep ----------------
// Wn_sw flat idx = ((kk*64 + w*8 + cg)*64 + lane)*8 + j
//   col = (cg>>1)*256 + (w*2 + (cg&1))*16 + (lane&15)   [gate = cg>>1]
//   k   = kk*32 + (lane>>4)*8 + j
// Wt_sw flat idx = (c8*512 + col)*8 + j ; value = Wt_rm[col][c8*8+j]
__global__ __launch_bounds__(512) void prep_kernel(
    const float* __restrict__ Wih_n, const float* __restrict__ Whh_n,
    const float* __restrict__ bih_n, const float* __restrict__ bhh_n,
    const float* __restrict__ Wih_t, const float* __restrict__ Whh_t,
    const float* __restrict__ bih_t, const float* __restrict__ bhh_t,
    const int* __restrict__ t_hist, const int* __restrict__ n_hist,
    f16* __restrict__ Wn, f16* __restrict__ Wt,
    float* __restrict__ bias_n, float* __restrict__ bias_t,
    int* __restrict__ gt_arr, int* __restrict__ gn_arr, float* __restrict__ cn_arr,
    int* __restrict__ last29p, unsigned* __restrict__ flags)
{
  const int gid = blockIdx.x * 512 + threadIdx.x;
  const int nthr = gridDim.x * 512;
  __shared__ int sgn[TMAX + 1];

  if (gid < 2 * NT) flags[gid] = 0u;

  for (int idx = gid; idx < GNN * KKA; idx += nthr) {
    const int j    = idx & 7;
    const int lane = (idx >> 3) & 63;
    const int cg   = (idx >> 9) & 7;
    const int w    = (idx >> 12) & 7;
    const int kk   = idx >> 15;
    const int col = (cg >> 1) * 256 + (w * 2 + (cg & 1)) * 16 + (lane & 15);
    const int k   = kk * 32 + (lane >> 4) * 8 + j;
    const float v = (k < EMB) ? Wih_n[col * EMB + k] : Whh_n[col * EDGE + (k - EMB)];
    Wn[idx] = (f16)v;
  }
  for (int idx = gid; idx < GTT * 192; idx += nthr) {
    const int j = idx & 7;
    const int col = (idx >> 3) & 511;
    const int c8 = idx >> 12;
    const int k = c8 * 8 + j;
    const float v = (k < EMB) ? Wih_t[col * EMB + k] : Whh_t[col * NODE + (k - EMB)];
    Wt[idx] = (f16)v;
  }
  for (int idx = gid; idx < GNN; idx += nthr) bias_n[idx] = bih_n[idx] + bhh_n[idx];
  for (int idx = gid; idx < GTT; idx += nthr) bias_t[idx] = bih_t[idx] + bhh_t[idx];

  if (blockIdx.x == 0 && threadIdx.x < 352) {
    const int t = (threadIdx.x >> 3) + 1;   // 1..44
    const int part = threadIdx.x & 7;
    int any_t = 0, cnt = 0;
    if (t < TOBS) {
      const int thr = TOBS - t;
      for (int nn = part; nn < NT; nn += 8) any_t |= (t_hist[nn] > thr) ? 1 : 0;
      for (int m = part; m < NT * KN; m += 8) cnt += (n_hist[m] > thr) ? 1 : 0;
    } else { any_t = (part == 0); cnt = (part == 0) ? NT * KN : 0; }
    #pragma unroll
    for (int off = 1; off < 8; off <<= 1) {
      any_t |= __shfl_xor(any_t, off);
      cnt   += __shfl_xor(cnt, off);
    }
    if (part == 0) {
      const int gn = (any_t && cnt > 0) ? 1 : 0;
      gt_arr[t] = any_t;
      gn_arr[t] = gn;
      cn_arr[t] = (float)cnt;
      sgn[t] = gn;
    }
  }
  __syncthreads();
  if (blockIdx.x == 0 && threadIdx.x == 0) {
    int l = 30;
    for (int t = 29; t >= 1; --t) if (sgn[t]) { l = t; break; }
    last29p[0] = l;
  }
}

// ---------------- main: TWO 512-thread blocks per target (NEIGHBOR-ROW halves) ----------------
// Block hb owns neighbors [hb*24, hb*24+24): recurrence fully local, zero exchange.
// Each block computes ALL 1024 gate cols for its 24(+8 pad) rows; wave w covers
// e-groups {2w, 2w+1} x 4 gates (cg = gate*2 + (eg-2w)). Target LSTM replicated.
// Only cross-block traffic: 1KB partial-Ht sum on att steps (flag store/poll).
__global__ __launch_bounds__(512, 2) void model_kernel(
    const float* __restrict__ img, const float* __restrict__ tabs,
    const float* __restrict__ trel, const float* __restrict__ tstep,
    const float* __restrict__ nabs_g, const float* __restrict__ nstep_g,
    const int* __restrict__ thist_g, const int* __restrict__ nhist_g,
    const float* __restrict__ W_disp, const float* __restrict__ b_disp,
    const float* __restrict__ W_att_t, const float* __restrict__ b_att_t,
    const float* __restrict__ W_att_n, const float* __restrict__ b_att_n,
    const float* __restrict__ W_pred, const float* __restrict__ b_pred,
    const f16* __restrict__ Wn, const f16* __restrict__ Wt,
    const float* __restrict__ bias_n, const float* __restrict__ bias_t,
    const int* __restrict__ gt_arr, const int* __restrict__ gn_arr,
    const float* __restrict__ cn_arr, const int* __restrict__ last29p,
    unsigned* __restrict__ flags, float* __restrict__ Pglob,
    float* __restrict__ out)
{
  __shared__ f16 s_wlds[32768];     // unit kk0 LDS-resident (64 KB)
  __shared__ f16 Ax[32][72];        // local rows 0..23 + 8 zero pad
  __shared__ f16 Ah[32][264];
  __shared__ float s_tht[NODE], s_tct[NODE];
  __shared__ f16  s_th16[NODE];
  __shared__ float s_Ht[EDGE];
  __shared__ f16  s_x16[EMB];
  __shared__ float s_g[GTT];
  __shared__ float s_bt[GTT];
  __shared__ float s_at[ATTD];
  __shared__ float s_sc[KN], s_w[KN];
  __shared__ float s_scal[8];
  __shared__ float s_pimg[2];
  __shared__ int   s_nh[KN];
  __shared__ float s_wp[2][384];
  __shared__ float s_wan0[ATTD], s_wan1[ATTD], s_ban[ATTD];
  __shared__ float s_wat0[ATTD], s_wat1[ATTD], s_bat[ATTD];
  __shared__ float s_wd0[EMB], s_wd1[EMB], s_bd[EMB];

  const int tid  = threadIdx.x;
  const int n    = blockIdx.x & 63;
  const int hb   = blockIdx.x >> 6;   // row half; (n, n+64) pair on same XCD
  const int w    = tid >> 6;
  const int lane = tid & 63;
  const int cl   = lane & 15;
  const int kq   = lane >> 4;
  const int koff = kq * 8;

  // ---- one-time init ----
  for (int i = tid; i < 32 * 264; i += 512) ((f16*)Ah)[i] = (f16)0.f;
  for (int i = tid; i < 32 * 72; i += 512) ((f16*)Ax)[i] = (f16)0.f;
  for (int i = tid; i < NODE; i += 512) { s_tht[i] = 0.f; s_tct[i] = 0.f; s_th16[i] = (f16)0.f; }
  for (int i = tid; i < EDGE; i += 512) s_Ht[i] = 0.f;
  for (int i = tid; i < GTT; i += 512) s_bt[i] = bias_t[i];
  for (int i = tid; i < 768; i += 512) {
    const int ww = i / 384, j = i - ww * 384;
    s_wp[ww][j] = (j < 128) ? W_pred[ww * 896 + j] : W_pred[ww * 896 + 640 + (j - 128)];
  }
  if (tid < KN) s_nh[tid] = nhist_g[n * KN + tid];
  if (tid < 8) s_scal[tid] = 0.f;
  if (tid >= 64 && tid < 128) {
    const int a = tid - 64;
    s_wan0[a] = W_att_n[a * 2]; s_wan1[a] = W_att_n[a * 2 + 1]; s_ban[a] = b_att_n[a];
  }
  if (tid >= 128 && tid < 192) {
    const int a = tid - 128;
    s_wat0[a] = W_att_t[a * 2]; s_wat1[a] = W_att_t[a * 2 + 1]; s_bat[a] = b_att_t[a];
  }
  if (tid >= 192 && tid < 256) {
    const int e = tid - 192;
    s_wd0[e] = W_disp[e * 2]; s_wd1[e] = W_disp[e * 2 + 1]; s_bd[e] = b_disp[e];
  }
  const int thist = thist_g[n];
  const int last29 = last29p[0];

  // resident unit kk0 = first 32768 f16 of Wn
  for (int i = tid * 8; i < 32768; i += 512 * 8)
    *(f16x8*)(s_wlds + i) = *(const f16x8*)(Wn + i);

  if (w < 2) {
    float s = 0.f;
    for (int j = lane; j < CNN; j += 64) s += img[n * CNN + j] * W_pred[w * 896 + 128 + j];
    for (int off = 32; off; off >>= 1) s += __shfl_down(s, off);
    if (lane == 0) s_pimg[w] = s + b_pred[w];
  }

  // per-lane state: rows rt*16+kq*4+jj (valid<24), e = (w*2+h2)*16+cl
  float creg[2][2][4];
  #pragma unroll
  for (int a = 0; a < 2; ++a)
    #pragma unroll
    for (int b = 0; b < 2; ++b)
      #pragma unroll
      for (int c = 0; c < 4; ++c) creg[a][b][c] = 0.f;

  float bias_q[8];
  #pragma unroll
  for (int cg = 0; cg < 8; ++cg)
    bias_q[cg] = bias_n[(cg >> 1) * 256 + (w * 2 + (cg & 1)) * 16 + cl];

  const f16* gW = Wn + (size_t)w * 4096 + (size_t)lane * 8;      // + kk*32768 + cg*512
  const f16* lW = s_wlds + (size_t)w * 4096 + (size_t)lane * 8;  // + cg*512
  unsigned* myflag = flags + n * 2 + hb;
  unsigned* otflag = flags + n * 2 + (1 - hb);
  int an = 0;   // att-step counter

  __syncthreads();

  // ---- stage t=1 ----
  {
    for (int i = tid; i < RPB * EMB; i += 512) {
      const int k = i >> 6, e = i & 63;
      const int gk = hb * RPB + k;
      const float s0 = nstep_g[((n * KN + gk) * TOBS + 1) * 2 + 0];
      const float s1 = nstep_g[((n * KN + gk) * TOBS + 1) * 2 + 1];
      Ax[k][e] = (f16)(s0 * s_wd0[e] + s1 * s_wd1[e] + s_bd[e]);
    }
    if (tid < 2) {
      s_scal[tid]     = tabs[(n * TOBS + 1) * 2 + tid];
      s_scal[2 + tid] = trel[(n * TOBS + 1) * 2 + tid];
      s_scal[4 + tid] = tstep[(n * TOBS + 1) * 2 + tid];
    }
    if (tid >= 448) {
      const int e = tid - 448;
      const float a0 = tstep[(n * TOBS + 1) * 2 + 0], a1 = tstep[(n * TOBS + 1) * 2 + 1];
      s_x16[e] = (f16)(a0 * s_wd0[e] + a1 * s_wd1[e] + s_bd[e]);
    }
    if (tid >= 384 && tid < 448) {
      const int a = tid - 384;
      const float r0 = trel[(n * TOBS + 1) * 2 + 0], r1 = trel[(n * TOBS + 1) * 2 + 1];
      s_at[a] = r0 * s_wat0[a] + r1 * s_wat1[a] + s_bat[a];
    }
  }
  __syncthreads();

  for (int t = 1; t <= TMAX; ++t) {
    const bool is_obs = (t < TOBS);
    const int tc = is_obs ? t : (TOBS - 1);
    const int gate_t = gt_arr[t];
    const int gate_n = gn_arr[t];
    const float currN = cn_arr[t];
    const bool tmask = is_obs ? (thist > (TOBS - t)) : true;
    const bool do_t = gate_t && tmask;
    const bool do_att = gate_n && (t >= last29) && (t < TMAX);

    // ---- pred head: P0 (local) + x16/at staging ----
    if (!is_obs) {
      if (w < 2) {
        float s = 0.f;
        for (int j = lane; j < NODE; j += 64) s += s_tht[j] * s_wp[w][j];
        for (int j = lane; j < EDGE; j += 64) s += s_Ht[j] * s_wp[w][128 + j];
        for (int off = 32; off; off >>= 1) s += __shfl_down(s, off);
        if (lane == 0) {
          const float p = s + s_pimg[w];
          const float cabs = s_scal[w] + p;
          const float crel = s_scal[2 + w] + p;
          s_scal[w] = cabs; s_scal[2 + w] = crel; s_scal[4 + w] = p;
          if (hb == 0) out[(n * NPRED + (t - TOBS)) * 2 + w] = crel;
        }
      }
      __syncthreads();  // A
      if (tid >= 448) {
        const int e = tid - 448;
        s_x16[e] = (f16)(s_scal[4] * s_wd0[e] + s_scal[5] * s_wd1[e] + s_bd[e]);
      }
      if (tid >= 384 && tid < 448) {
        const int a = tid - 384;
        s_at[a] = s_scal[2] * s_wat0[a] + s_scal[3] * s_wat1[a] + s_bat[a];
      }
      __syncthreads();  // B
    }

    // ---- P2: nearby LSTM, own 24 rows, ALL 1024 cols ----
    f16 hreg[2][2][4];
    if (gate_n) {
      f32x4 acc[2][8];
      #pragma unroll
      for (int rt = 0; rt < 2; ++rt)
        #pragma unroll
        for (int cg = 0; cg < 8; ++cg) acc[rt][cg] = (f32x4){0.f, 0.f, 0.f, 0.f};

      #pragma unroll
      for (int kk = 0; kk < 10; ++kk) {
        f16x8 af0, af1;
        if (kk < 2) {
          af0 = *(const f16x8*)&Ax[cl][kk * 32 + koff];
          af1 = *(const f16x8*)&Ax[16 + cl][kk * 32 + koff];
        } else {
          af0 = *(const f16x8*)&Ah[cl][(kk - 2) * 32 + koff];
          af1 = *(const f16x8*)&Ah[16 + cl][(kk - 2) * 32 + koff];
        }
        #pragma unroll
        for (int cg = 0; cg < 8; ++cg) {
          const f16x8 bf = (kk == 0)
              ? *(const f16x8*)(lW + cg * 512)
              : *(const f16x8*)(gW + (size_t)kk * 32768 + cg * 512);
          acc[0][cg] = __builtin_amdgcn_mfma_f32_16x16x32_f16(af0, bf, acc[0][cg], 0, 0, 0);
          acc[1][cg] = __builtin_amdgcn_mfma_f32_16x16x32_f16(af1, bf, acc[1][cg], 0, 0, 0);
        }
      }

      #pragma unroll
      for (int rt = 0; rt < 2; ++rt) {
        #pragma unroll
        for (int jj = 0; jj < 4; ++jj) {
          const int row = rt * 16 + kq * 4 + jj;
          const bool valid = row < RPB;
          const bool nm = valid && (is_obs ? (s_nh[hb * RPB + row] > (TOBS - t)) : true);
          #pragma unroll
          for (int h2 = 0; h2 < 2; ++h2) {
            if (nm) {
              const float iv = acc[rt][0 + h2][jj] + bias_q[0 + h2];
              const float fv = acc[rt][2 + h2][jj] + bias_q[2 + h2];
              const float gv = acc[rt][4 + h2][jj] + bias_q[4 + h2];
              const float ov = acc[rt][6 + h2][jj] + bias_q[6 + h2];
              const float c2 = sigm(fv) * creg[rt][h2][jj] + sigm(iv) * tanh_f(gv);
              creg[rt][h2][jj] = c2;
              hreg[rt][h2][jj] = (f16)(sigm(ov) * tanh_f(c2));
            } else {
              hreg[rt][h2][jj] = Ah[row][(w * 2 + h2) * 16 + cl];
            }
          }
        }
      }
    }

    // ---- P3: target gate dots, replicated (all 512 cols) ----
    if (do_t) {
      float gg = s_bt[tid];
      const f16x2* xt2 = (const f16x2*)s_x16;
      const f16x2* th2 = (const f16x2*)s_th16;
      const f16x8* wp = (const f16x8*)(Wt + tid * 8);
      #pragma unroll
      for (int c8 = 0; c8 < 8; ++c8) {
        const f16x8 wv = wp[c8 * 512];
        #pragma unroll
        for (int j2 = 0; j2 < 4; ++j2) {
          f16x2 wpair = {wv[2 * j2], wv[2 * j2 + 1]};
          gg = __builtin_amdgcn_fdot2(wpair, xt2[c8 * 4 + j2], gg, false);
        }
      }
      #pragma unroll
      for (int c8 = 8; c8 < 24; ++c8) {
        const f16x8 wv = wp[c8 * 512];
        #pragma unroll
        for (int j2 = 0; j2 < 4; ++j2) {
          f16x2 wpair = {wv[2 * j2], wv[2 * j2 + 1]};
          gg = __builtin_amdgcn_fdot2(wpair, th2[(c8 - 8) * 4 + j2], gg, false);
        }
      }
      s_g[tid] = gg;
    }
    if (gate_n || do_t) __syncthreads();  // C1

    // ---- post-C1: Ah write, cell update, scores, prestage ----
    if (gate_n) {
      #pragma unroll
      for (int rt = 0; rt < 2; ++rt)
        #pragma unroll
        for (int jj = 0; jj < 4; ++jj) {
          const int row = rt * 16 + kq * 4 + jj;
          if (row < RPB) {
            #pragma unroll
            for (int h2 = 0; h2 < 2; ++h2)
              Ah[row][(w * 2 + h2) * 16 + cl] = hreg[rt][h2][jj];
          }
        }
    }
    if (do_t && tid < NODE) {
      const float iv = s_g[tid], fv = s_g[NODE + tid];
      const float gv = s_g[2 * NODE + tid], ov = s_g[3 * NODE + tid];
      const float c2 = sigm(fv) * s_tct[tid] + sigm(iv) * tanh_f(gv);
      s_tct[tid] = c2;
      const float nh = sigm(ov) * tanh_f(c2);
      s_tht[tid] = nh;
      s_th16[tid] = (f16)nh;
    }
    if (do_att && tid >= 128 && tid < 128 + KN) {
      const int k = tid - 128;
      const float a0 = nabs_g[((n * KN + k) * TOBS + tc) * 2 + 0] - s_scal[0];
      const float a1 = nabs_g[((n * KN + k) * TOBS + tc) * 2 + 1] - s_scal[1];
      const bool nm = is_obs ? (s_nh[k] > (TOBS - t)) : true;
      float sc = 0.f;
      for (int a = 0; a < ATTD; ++a)
        sc += (a0 * s_wan0[a] + a1 * s_wan1[a] + s_ban[a]) * s_at[a];
      sc *= currN * 0.125f;
      s_sc[k] = nm ? sc : 0.f;
      s_w[k]  = nm ? 1.f : 0.f;
    }
    // prestage next Ax (P2 reads finished at C1)
    {
      const int tn = t + 1;
      if (tn <= TOBS) {
        const int tcn = (tn < TOBS) ? tn : (TOBS - 1);
        for (int i = tid; i < RPB * EMB; i += 512) {
          const int k = i >> 6, e = i & 63;
          const int gk = hb * RPB + k;
          const float s0 = nstep_g[((n * KN + gk) * TOBS + tcn) * 2 + 0];
          const float s1 = nstep_g[((n * KN + gk) * TOBS + tcn) * 2 + 1];
          Ax[k][e] = (f16)(s0 * s_wd0[e] + s1 * s_wd1[e] + s_bd[e]);
        }
      }
      // scalar prestage: on att steps s_scal is still read by scores -> delay to post-C2
      if (!do_att && tn < TOBS) {
        if (tid < 2) {
          s_scal[tid]     = tabs[(n * TOBS + tn) * 2 + tid];
          s_scal[2 + tid] = trel[(n * TOBS + tn) * 2 + tid];
          s_scal[4 + tid] = tstep[(n * TOBS + tn) * 2 + tid];
        }
        if (tid >= 448) {
          const int e = tid - 448;
          const float a0 = tstep[(n * TOBS + tn) * 2 + 0], a1 = tstep[(n * TOBS + tn) * 2 + 1];
          s_x16[e] = (f16)(a0 * s_wd0[e] + a1 * s_wd1[e] + s_bd[e]);
        }
        if (tid >= 384 && tid < 448) {
          const int a = tid - 384;
          const float r0 = trel[(n * TOBS + tn) * 2 + 0], r1 = trel[(n * TOBS + tn) * 2 + 1];
          s_at[a] = r0 * s_wat0[a] + r1 * s_wat1[a] + s_bat[a];
        }
      }
    }

    // ---- att steps: softmax + partial-Ht exchange (the only cross-block traffic) ----
    if (do_att) {
      __syncthreads();  // C2 (scores + Ah ready)
      if (w == 7) {
        const bool act = lane < KN;
        const float sc = act ? s_sc[lane] : -1.0e30f;
        const float mf = act ? s_w[lane] : 0.f;
        float mx = sc;
        #pragma unroll
        for (int off = 32; off; off >>= 1) mx = fmaxf(mx, __shfl_xor(mx, off));
        float num = __expf(sc - mx) * mf;
        float sum = num;
        #pragma unroll
        for (int off = 32; off; off >>= 1) sum += __shfl_xor(sum, off);
        if (act) s_w[lane] = num * rcp_f(sum + 1e-6f);
      }
      // scalar prestage (delayed): scores done reading s_scal
      {
        const int tn = t + 1;
        if (tn < TOBS) {
          if (tid < 2) {
            s_scal[tid]     = tabs[(n * TOBS + tn) * 2 + tid];
            s_scal[2 + tid] = trel[(n * TOBS + tn) * 2 + tid];
            s_scal[4 + tid] = tstep[(n * TOBS + tn) * 2 + tid];
          }
          if (tid >= 256 && tid < 320) {
            const int e = tid - 256;
            const float a0 = tstep[(n * TOBS + tn) * 2 + 0], a1 = tstep[(n * TOBS + tn) * 2 + 1];
            s_x16[e] = (f16)(a0 * s_wd0[e] + a1 * s_wd1[e] + s_bd[e]);
          }
          if (tid >= 320 && tid < 384) {
            const int a = tid - 320;
            const float r0 = trel[(n * TOBS + tn) * 2 + 0], r1 = trel[(n * TOBS + tn) * 2 + 1];
            s_at[a] = r0 * s_wat0[a] + r1 * s_wat1[a] + s_bat[a];
          }
        }
      }
      __syncthreads();  // C3 (softmax weights ready)
      float own = 0.f;
      if (tid < EDGE) {
        #pragma unroll 4
        for (int k = 0; k < RPB; ++k)
          own += s_w[hb * RPB + k] * (float)Ah[k][tid];
        stcohf(Pglob + (size_t)(((an & 1) * 2 + hb) * NT + n) * EDGE + tid, own);
      }
      __syncthreads();  // C4: drains MALL stores (vmcnt(0) before s_barrier)
      if (tid == 0) {
        stcoh(myflag, (unsigned)(an + 1));
        while (ldcoh(otflag) < (unsigned)(an + 1)) __builtin_amdgcn_s_sleep(2);
      }
      __syncthreads();  // D
      if (tid < EDGE) {
        const float oth = ldcohf(Pglob + (size_t)(((an & 1) * 2 + (1 - hb)) * NT + n) * EDGE + tid);
        s_Ht[tid] = own + oth;
      }
      an++;
    }
    __syncthreads();  // F
  }
}

extern "C" void kernel_launch(void* const* d_in, const int* in_sizes, int n_in,
                              void* d_out, int out_size, void* d_ws, size_t ws_size,
                              hipStream_t stream) {
  const float* img    = (const float*)d_in[0];
  const float* tabs   = (const float*)d_in[1];
  const float* trel   = (const float*)d_in[2];
  const float* tstep  = (const float*)d_in[3];
  const float* nabs   = (const float*)d_in[4];
  const float* nstep  = (const float*)d_in[6];
  const int*   thist  = (const int*)d_in[7];
  const int*   nhist  = (const int*)d_in[8];
  const float* W_disp = (const float*)d_in[9];
  const float* b_disp = (const float*)d_in[10];
  const float* Wih_t  = (const float*)d_in[11];
  const float* Whh_t  = (const float*)d_in[12];
  const float* bih_t  = (const float*)d_in[13];
  const float* bhh_t  = (const float*)d_in[14];
  const float* Wih_n  = (const float*)d_in[15];
  const float* Whh_n  = (const float*)d_in[16];
  const float* bih_n  = (const float*)d_in[17];
  const float* bhh_n  = (const float*)d_in[18];
  const float* W_att_t = (const float*)d_in[19];
  const float* b_att_t = (const float*)d_in[20];
  const float* W_att_n = (const float*)d_in[21];
  const float* b_att_n = (const float*)d_in[22];
  const float* W_pred  = (const float*)d_in[23];
  const float* b_pred  = (const float*)d_in[24];

  char* ws = (char*)d_ws;
  f16*      Wn      = (f16*)(ws);              // 655360 B
  f16*      Wt      = (f16*)(ws + 655360);     // 196608 B
  float*    bias_n  = (float*)(ws + 851968);
  float*    bias_t  = (float*)(ws + 856064);
  int*      gt_arr  = (int*)(ws + 858112);
  int*      gn_arr  = (int*)(ws + 858304);
  float*    cn_arr  = (float*)(ws + 858496);
  int*      last29p = (int*)(ws + 859648);
  unsigned* flags   = (unsigned*)(ws + 860160);
  float*    Pglob   = (float*)(ws + 1048576);  // 2*2*64*256*4 = 262144 B

  prep_kernel<<<64, 512, 0, stream>>>(Wih_n, Whh_n, bih_n, bhh_n, Wih_t, Whh_t,
                                      bih_t, bhh_t, thist, nhist, Wn, Wt,
                                      bias_n, bias_t, gt_arr, gn_arr, cn_arr,
                                      last29p, flags);
  model_kernel<<<2 * NT, 512, 0, stream>>>(img, tabs, trel, tstep, nabs, nstep,
                                           thist, nhist, W_disp, b_disp,
                                           W_att_t, b_att_t, W_att_n, b_att_n,
                                           W_pred, b_pred,
                                           Wn, Wt, bias_n, bias_t,
                                           gt_arr, gn_arr, cn_arr, last29p,
                                           flags, Pglob,
                                           (float*)d_out);
}

// Round 13
// 722.577 us; speedup vs baseline: 1.7499x; 1.7499x over previous
//
#include <hip/hip_runtime.h>
#include <math.h>

#define NT 64
#define KN 48
#define TOBS 30
#define NPRED 15
#define EMB 64
#define NODE 128
#define EDGE 256
#define ATTD 64
#define CNN 512
#define GNN 1024
#define GTT 512
#define KKA 320
#define TMAX 44

typedef _Float16 f16;
typedef f16 f16x8 __attribute__((ext_vector_type(8)));
typedef f16 f16x2 __attribute__((ext_vector_type(2)));
typedef float f32x4 __attribute__((ext_vector_type(4)));

__device__ __forceinline__ float rcp_f(float x) { return __builtin_amdgcn_rcpf(x); }
__device__ __forceinline__ float sigm(float x) { return rcp_f(1.f + __expf(-x)); }
__device__ __forceinline__ float tanh_f(float x) {
  float xx = fminf(fmaxf(x, -20.f), 20.f);
  float e = __expf(-2.f * xx);
  return (1.f - e) * rcp_f(1.f + e);
}
__device__ __forceinline__ unsigned ldcoh(const unsigned* p) {
  return __hip_atomic_load(p, __ATOMIC_RELAXED, __HIP_MEMORY_SCOPE_AGENT);
}
__device__ __forceinline__ float ldcohf(const float* p) {
  unsigned u = __hip_atomic_load((const unsigned*)p, __ATOMIC_RELAXED, __HIP_MEMORY_SCOPE_AGENT);
  return __builtin_bit_cast(float, u);
}
__device__ __forceinline__ void stcoh(unsigned* p, unsigned v) {
  __hip_atomic_store(p, v, __ATOMIC_RELAXED, __HIP_MEMORY_SCOPE_AGENT);
}
__device__ __forceinline__ void stcohf(float* p, float v) {
  __hip_atomic_store((unsigned*)p, __builtin_bit_cast(unsigned, v),
                     __ATOMIC_RELAXED, __HIP_MEMORY_SCOPE_AGENT);
}
// async global->LDS: lane i's 16B land at (wave-uniform) lds base + i*16
__device__ __forceinline__ void glds16(const f16* g, const f16* l) {
  __builtin_amdgcn_global_load_lds(
      (const __attribute__((address_space(1))) void*)g,
      (__attribute__((address_space(3))) void*)l, 16, 0, 0);
}

// ---------------- prep ----------------
// Wn_sw flat idx = ((((h*8+w)*10 + kk)*4 + g)*64 + lane)*8 + j
//   value = Wn_rm[col][k], col = g*256 + h*128 + w*16 + (lane&15), k = kk*32 + (lane>>4)*8 + j
// Wt_sw flat idx = (c8*512 + col)*8 + j ; value = Wt_rm[col][c8*8+j]
__global__ __launch_bounds__(512) void prep_kernel(
    const float* __restrict__ Wih_n, const float* __restrict__ Whh_n,
    const float* __restrict__ bih_n, const float* __restrict__ bhh_n,
    const float* __restrict__ Wih_t, const float* __restrict__ Whh_t,
    const float* __restrict__ bih_t, const float* __restrict__ bhh_t,
    const int* __restrict__ t_hist, const int* __restrict__ n_hist,
    f16* __restrict__ Wn, f16* __restrict__ Wt,
    float* __restrict__ bias_n, float* __restrict__ bias_t,
    int* __restrict__ gt_arr, int* __restrict__ gn_arr, float* __restrict__ cn_arr,
    int* __restrict__ last29p, unsigned* __restrict__ flags)
{
  const int gid = blockIdx.x * 512 + threadIdx.x;
  const int nthr = gridDim.x * 512;
  __shared__ int sgn[TMAX + 1];

  if (gid < 2 * NT) flags[gid] = 0u;

  for (int idx = gid; idx < GNN * KKA; idx += nthr) {
    const int j    = idx & 7;
    const int lane = (idx >> 3) & 63;
    const int g    = (idx >> 9) & 3;
    const int r    = idx >> 11;
    const int kk   = r % 10;
    const int s    = r / 10;
    const int w    = s & 7;
    const int h    = s >> 3;
    const int col = g * 256 + h * 128 + w * 16 + (lane & 15);
    const int k   = kk * 32 + (lane >> 4) * 8 + j;
    const float v = (k < EMB) ? Wih_n[col * EMB + k] : Whh_n[col * EDGE + (k - EMB)];
    Wn[idx] = (f16)v;
  }
  for (int idx = gid; idx < GTT * 192; idx += nthr) {
    const int j = idx & 7;
    const int col = (idx >> 3) & 511;
    const int c8 = idx >> 12;
    const int k = c8 * 8 + j;
    const float v = (k < EMB) ? Wih_t[col * EMB + k] : Whh_t[col * NODE + (k - EMB)];
    Wt[idx] = (f16)v;
  }
  for (int idx = gid; idx < GNN; idx += nthr) bias_n[idx] = bih_n[idx] + bhh_n[idx];
  for (int idx = gid; idx < GTT; idx += nthr) bias_t[idx] = bih_t[idx] + bhh_t[idx];

  if (blockIdx.x == 0 && threadIdx.x < 352) {
    const int t = (threadIdx.x >> 3) + 1;   // 1..44
    const int part = threadIdx.x & 7;
    int any_t = 0, cnt = 0;
    if (t < TOBS) {
      const int thr = TOBS - t;
      for (int nn = part; nn < NT; nn += 8) any_t |= (t_hist[nn] > thr) ? 1 : 0;
      for (int m = part; m < NT * KN; m += 8) cnt += (n_hist[m] > thr) ? 1 : 0;
    } else { any_t = (part == 0); cnt = (part == 0) ? NT * KN : 0; }
    #pragma unroll
    for (int off = 1; off < 8; off <<= 1) {
      any_t |= __shfl_xor(any_t, off);
      cnt   += __shfl_xor(cnt, off);
    }
    if (part == 0) {
      const int gn = (any_t && cnt > 0) ? 1 : 0;
      gt_arr[t] = any_t;
      gn_arr[t] = gn;
      cn_arr[t] = (float)cnt;
      sgn[t] = gn;
    }
  }
  __syncthreads();
  if (blockIdx.x == 0 && threadIdx.x == 0) {
    int l = 30;
    for (int t = 29; t >= 1; --t) if (sgn[t]) { l = t; break; }
    last29p[0] = l;
  }
}

// ---------------- main: TWO 512-thread blocks per target (e-halves) ----------------
// R9 structure. P2 weights streamed via wave-private global_load_lds triple-buffered
// ring with HAND-PLACED s_waitcnt vmcnt(4) (depth-2 prefetch; the compiler cannot see
// the DMA->LDS->ds_read dependency, so the wait must be explicit).
__global__ __launch_bounds__(512, 2) void model_kernel(
    const float* __restrict__ img, const float* __restrict__ tabs,
    const float* __restrict__ trel, const float* __restrict__ tstep,
    const float* __restrict__ nabs_g, const float* __restrict__ nstep_g,
    const int* __restrict__ thist_g, const int* __restrict__ nhist_g,
    const float* __restrict__ W_disp, const float* __restrict__ b_disp,
    const float* __restrict__ W_att_t, const float* __restrict__ b_att_t,
    const float* __restrict__ W_att_n, const float* __restrict__ b_att_n,
    const float* __restrict__ W_pred, const float* __restrict__ b_pred,
    const f16* __restrict__ Wn, const f16* __restrict__ Wt,
    const float* __restrict__ bias_n, const float* __restrict__ bias_t,
    const int* __restrict__ gt_arr, const int* __restrict__ gn_arr,
    const float* __restrict__ cn_arr, const int* __restrict__ last29p,
    unsigned* __restrict__ flags, unsigned* __restrict__ Hglob,
    float* __restrict__ Tglob,
    float* __restrict__ out)
{
  __shared__ __attribute__((aligned(16))) f16 s_wbuf[8 * 6144]; // per-wave 3x4KB ring
  __shared__ f16 Ax[KN][72];
  __shared__ f16 Ah[KN][264];
  __shared__ float s_tht[NODE];
  __shared__ float s_tct[64];
  __shared__ f16  s_th16[NODE];
  __shared__ float s_Ht[EDGE];
  __shared__ f16  s_x16[EMB];
  __shared__ float s_g[256];
  __shared__ float s_bt[256];
  __shared__ float s_at[ATTD];
  __shared__ float s_sc[KN], s_w[KN];
  __shared__ float s_scal[8];
  __shared__ float s_pimg[2];
  __shared__ int   s_nh[KN];
  __shared__ float s_wp[2][384];
  __shared__ float s_wan0[ATTD], s_wan1[ATTD], s_ban[ATTD];
  __shared__ float s_wat0[ATTD], s_wat1[ATTD], s_bat[ATTD];
  __shared__ float s_wd0[EMB], s_wd1[EMB], s_bd[EMB];

  const int tid  = threadIdx.x;
  const int n    = blockIdx.x & 63;
  const int hb   = blockIdx.x >> 6;
  const int w    = tid >> 6;
  const int lane = tid & 63;
  const int cl   = lane & 15;
  const int kq   = lane >> 4;
  const int koff = kq * 8;

  // ---- one-time init ----
  for (int i = tid; i < KN * 264; i += 512) ((f16*)Ah)[i] = (f16)0.f;
  for (int i = tid; i < NODE; i += 512) { s_tht[i] = 0.f; s_th16[i] = (f16)0.f; }
  if (tid < 64) s_tct[tid] = 0.f;
  for (int i = tid; i < EDGE; i += 512) s_Ht[i] = 0.f;
  if (tid < 256) {
    const int g = tid >> 6, dl = tid & 63;
    s_bt[tid] = bias_t[g * 128 + hb * 64 + dl];
  }
  for (int i = tid; i < 768; i += 512) {
    const int ww = i / 384, j = i - ww * 384;
    s_wp[ww][j] = (j < 128) ? W_pred[ww * 896 + j] : W_pred[ww * 896 + 640 + (j - 128)];
  }
  if (tid < KN) s_nh[tid] = nhist_g[n * KN + tid];
  if (tid < 8) s_scal[tid] = 0.f;
  if (tid >= 64 && tid < 128) {
    const int a = tid - 64;
    s_wan0[a] = W_att_n[a * 2]; s_wan1[a] = W_att_n[a * 2 + 1]; s_ban[a] = b_att_n[a];
  }
  if (tid >= 128 && tid < 192) {
    const int a = tid - 128;
    s_wat0[a] = W_att_t[a * 2]; s_wat1[a] = W_att_t[a * 2 + 1]; s_bat[a] = b_att_t[a];
  }
  if (tid >= 192 && tid < 256) {
    const int e = tid - 192;
    s_wd0[e] = W_disp[e * 2]; s_wd1[e] = W_disp[e * 2 + 1]; s_bd[e] = b_disp[e];
  }
  const int thist = thist_g[n];
  const int last29 = last29p[0];

  if (w < 2) {
    float s = 0.f;
    for (int j = lane; j < CNN; j += 64) s += img[n * CNN + j] * W_pred[w * 896 + 128 + j];
    for (int off = 32; off; off >>= 1) s += __shfl_down(s, off);
    if (lane == 0) s_pimg[w] = s + b_pred[w];
  }

  float creg[3][4];
  #pragma unroll
  for (int b = 0; b < 3; ++b)
    #pragma unroll
    for (int c = 0; c < 4; ++c) creg[b][c] = 0.f;

  float bias_q[4];
  #pragma unroll
  for (int g = 0; g < 4; ++g) bias_q[g] = bias_n[g * 256 + hb * 128 + w * 16 + cl];

  // weight stream pointers: per-lane global source, wave-uniform LDS ring dest
  const f16* gW  = Wn + ((size_t)(hb * 8 + w) * 10) * 2048 + (size_t)lane * 8;  // +kk*2048+g*512
  f16* wbW = s_wbuf + (size_t)w * 6144;                                         // +(kk%3)*2048+g*512
  const f16* wbR = wbW + (size_t)lane * 8;                                      // read side
  const int e_g = hb * 128 + w * 16 + cl;
  unsigned* myflag = flags + n * 2 + hb;
  unsigned* otflag = flags + n * 2 + (1 - hb);
  int bn = 0;

  __syncthreads();

  // ---- stage t=1 (obs) ----
  {
    for (int i = tid; i < KN * EMB; i += 512) {
      const int k = i >> 6, e = i & 63;
      const float s0 = nstep_g[((n * KN + k) * TOBS + 1) * 2 + 0];
      const float s1 = nstep_g[((n * KN + k) * TOBS + 1) * 2 + 1];
      Ax[k][e] = (f16)(s0 * s_wd0[e] + s1 * s_wd1[e] + s_bd[e]);
    }
    if (tid < 2) {
      s_scal[tid]     = tabs[(n * TOBS + 1) * 2 + tid];
      s_scal[2 + tid] = trel[(n * TOBS + 1) * 2 + tid];
      s_scal[4 + tid] = tstep[(n * TOBS + 1) * 2 + tid];
    }
    if (tid >= 448) {
      const int e = tid - 448;
      const float a0 = tstep[(n * TOBS + 1) * 2 + 0], a1 = tstep[(n * TOBS + 1) * 2 + 1];
      s_x16[e] = (f16)(a0 * s_wd0[e] + a1 * s_wd1[e] + s_bd[e]);
    }
    if (tid >= 384 && tid < 448) {
      const int a = tid - 384;
      const float r0 = trel[(n * TOBS + 1) * 2 + 0], r1 = trel[(n * TOBS + 1) * 2 + 1];
      s_at[a] = r0 * s_wat0[a] + r1 * s_wat1[a] + s_bat[a];
    }
  }
  __syncthreads();

  for (int t = 1; t <= TMAX; ++t) {
    const bool is_obs = (t < TOBS);
    const int tc = is_obs ? t : (TOBS - 1);
    const int gate_t = gt_arr[t];
    const int gate_n = gn_arr[t];
    const float currN = cn_arr[t];
    const bool tmask = is_obs ? (thist > (TOBS - t)) : true;
    const bool do_t = gate_t && tmask;
    const bool need_x = (gate_n || do_t);
    const int par = bn & 1;

    // ---- pred-step top: P0 + x16/at staging (obs steps prestaged last iter) ----
    if (!is_obs) {
      if (w < 2) {
        float s = 0.f;
        for (int j = lane; j < NODE; j += 64) s += s_tht[j] * s_wp[w][j];
        for (int j = lane; j < EDGE; j += 64) s += s_Ht[j] * s_wp[w][128 + j];
        for (int off = 32; off; off >>= 1) s += __shfl_down(s, off);
        if (lane == 0) {
          const float p = s + s_pimg[w];
          const float cabs = s_scal[w] + p;
          const float crel = s_scal[2 + w] + p;
          s_scal[w] = cabs; s_scal[2 + w] = crel; s_scal[4 + w] = p;
          if (hb == 0) out[(n * NPRED + (t - TOBS)) * 2 + w] = crel;
        }
      }
      __syncthreads();  // A
      if (tid >= 448) {
        const int e = tid - 448;
        s_x16[e] = (f16)(s_scal[4] * s_wd0[e] + s_scal[5] * s_wd1[e] + s_bd[e]);
      }
      if (tid >= 384 && tid < 448) {
        const int a = tid - 384;
        s_at[a] = s_scal[2] * s_wat0[a] + s_scal[3] * s_wat1[a] + s_bat[a];
      }
      __syncthreads();  // B
    }

    // ---- P2: nearby LSTM via MFMA; wave-private LDS-DMA weight ring ----
    f16 hreg[3][4];
    if (gate_n) {
      f32x4 acc[3][4];
      #pragma unroll
      for (int rt = 0; rt < 3; ++rt)
        #pragma unroll
        for (int g = 0; g < 4; ++g) acc[rt][g] = (f32x4){0.f, 0.f, 0.f, 0.f};

      // prologue: prefetch units 0,1 into ring slots 0,1 (8 DMAs in flight)
      #pragma unroll
      for (int kp = 0; kp < 2; ++kp)
        #pragma unroll
        for (int g = 0; g < 4; ++g)
          glds16(gW + kp * 2048 + g * 512, wbW + kp * 2048 + g * 512);

      #pragma unroll
      for (int kk = 0; kk < 10; ++kk) {
        // REQUIRED: wait unit kk's 4 DMAs (vmcnt tracks global_load_lds; the
        // compiler cannot see the DMA->ds_read dependency). Keep next unit in flight.
        if (kk == 9) { asm volatile("s_waitcnt vmcnt(0)" ::: "memory"); }
        else         { asm volatile("s_waitcnt vmcnt(4)" ::: "memory"); }

        f16x8 bf[4];
        #pragma unroll
        for (int g = 0; g < 4; ++g)
          bf[g] = *(const f16x8*)(wbR + (kk % 3) * 2048 + g * 512);

        if (kk < 8) {
          const int slot = (kk + 2) % 3;
          #pragma unroll
          for (int g = 0; g < 4; ++g)
            glds16(gW + (kk + 2) * 2048 + g * 512, wbW + slot * 2048 + g * 512);
        }

        f16x8 af[3];
        #pragma unroll
        for (int rt = 0; rt < 3; ++rt) {
          const int row = rt * 16 + cl;
          const f16* ap = (kk < 2) ? &Ax[row][kk * 32 + koff]
                                   : &Ah[row][(kk - 2) * 32 + koff];
          af[rt] = *(const f16x8*)ap;
        }
        #pragma unroll
        for (int g = 0; g < 4; ++g)
          #pragma unroll
          for (int rt = 0; rt < 3; ++rt)
            acc[rt][g] = __builtin_amdgcn_mfma_f32_16x16x32_f16(af[rt], bf[g], acc[rt][g], 0, 0, 0);
      }

      unsigned* Hg = Hglob + (size_t)(par * NT + n) * (KN * 128);
      #pragma unroll
      for (int rt = 0; rt < 3; ++rt) {
        #pragma unroll
        for (int jj = 0; jj < 4; ++jj) {
          const int row = rt * 16 + kq * 4 + jj;
          const bool nm = is_obs ? (s_nh[row] > (TOBS - t)) : true;
          f16 hv;
          if (nm) {
            const float iv = acc[rt][0][jj] + bias_q[0];
            const float fv = acc[rt][1][jj] + bias_q[1];
            const float gv = acc[rt][2][jj] + bias_q[2];
            const float ov = acc[rt][3][jj] + bias_q[3];
            const float c2 = sigm(fv) * creg[rt][jj] + sigm(iv) * tanh_f(gv);
            creg[rt][jj] = c2;
            hv = (f16)(sigm(ov) * tanh_f(c2));
          } else {
            hv = Ah[row][e_g];
          }
          hreg[rt][jj] = hv;
          const unsigned lo = (unsigned)__builtin_bit_cast(unsigned short, hv);
          const unsigned hi = (unsigned)__shfl_down((int)lo, 1);
          if (!(cl & 1))
            stcoh(Hg + row * 128 + (e_g >> 1), lo | (hi << 16));
        }
      }
    }

    // ---- target gate dots (own 4 gates x 64 node dims) ----
    if (do_t && tid < 256) {
      const int g = tid >> 6, dl = tid & 63;
      const int col = g * 128 + hb * 64 + dl;
      float gg = s_bt[tid];
      const f16x2* xt2 = (const f16x2*)s_x16;
      const f16x2* th2 = (const f16x2*)s_th16;
      const f16x8* wp = (const f16x8*)(Wt + col * 8);
      #pragma unroll
      for (int c8 = 0; c8 < 8; ++c8) {
        const f16x8 wv = wp[c8 * 512];
        #pragma unroll
        for (int j2 = 0; j2 < 4; ++j2) {
          f16x2 wpair = {wv[2 * j2], wv[2 * j2 + 1]};
          gg = __builtin_amdgcn_fdot2(wpair, xt2[c8 * 4 + j2], gg, false);
        }
      }
      #pragma unroll
      for (int c8 = 8; c8 < 24; ++c8) {
        const f16x8 wv = wp[c8 * 512];
        #pragma unroll
        for (int j2 = 0; j2 < 4; ++j2) {
          f16x2 wpair = {wv[2 * j2], wv[2 * j2 + 1]};
          gg = __builtin_amdgcn_fdot2(wpair, th2[(c8 - 8) * 4 + j2], gg, false);
        }
      }
      s_g[tid] = gg;
    }
    // ---- attention scores (only t >= last29) ----
    const bool do_att = gate_n && (t >= last29);
    if (do_att && tid >= 256 && tid < 256 + KN) {
      const int k = tid - 256;
      const float a0 = nabs_g[((n * KN + k) * TOBS + tc) * 2 + 0] - s_scal[0];
      const float a1 = nabs_g[((n * KN + k) * TOBS + tc) * 2 + 1] - s_scal[1];
      const bool nm = is_obs ? (s_nh[k] > (TOBS - t)) : true;
      float sc = 0.f;
      for (int a = 0; a < ATTD; ++a)
        sc += (a0 * s_wan0[a] + a1 * s_wan1[a] + s_ban[a]) * s_at[a];
      sc *= currN * 0.125f;
      s_sc[k] = nm ? sc : 0.f;
      s_w[k]  = nm ? 1.f : 0.f;
    }
    __syncthreads();  // C1

    // ---- cell update + publish; softmax ----
    if (do_t && tid < 64) {
      const int d = hb * 64 + tid;
      const float iv = s_g[tid], fv = s_g[64 + tid];
      const float gv = s_g[128 + tid], ov = s_g[192 + tid];
      const float c2 = sigm(fv) * s_tct[tid] + sigm(iv) * tanh_f(gv);
      s_tct[tid] = c2;
      const float nh = sigm(ov) * tanh_f(c2);
      s_tht[d] = nh;
      s_th16[d] = (f16)nh;
      stcohf(Tglob + ((size_t)(par * NT + n) * 2 + hb) * 64 + tid, nh);
    }
    if (do_att && w == 4) {
      const bool act = lane < KN;
      const float sc = act ? s_sc[lane] : -1.0e30f;
      const float mf = act ? s_w[lane] : 0.f;
      float mx = sc;
      #pragma unroll
      for (int off = 32; off; off >>= 1) mx = fmaxf(mx, __shfl_xor(mx, off));
      float num = __expf(sc - mx) * mf;
      float sum = num;
      #pragma unroll
      for (int off = 32; off; off >>= 1) sum += __shfl_xor(sum, off);
      if (act) s_w[lane] = num * rcp_f(sum + 1e-6f);
    }
    __syncthreads();  // C2: drains all MALL stores (vmcnt(0) before s_barrier)

    if (need_x && tid == 0) {
      stcoh(myflag, (unsigned)(bn + 1));   // publish
    }

    // ---- prestage t+1 (off the serial path, while partner finishes) ----
    {
      const int tn = t + 1;
      if (tn <= TOBS) {
        const int tcn = (tn < TOBS) ? tn : (TOBS - 1);
        for (int i = tid; i < KN * EMB; i += 512) {
          const int k = i >> 6, e = i & 63;
          const float s0 = nstep_g[((n * KN + k) * TOBS + tcn) * 2 + 0];
          const float s1 = nstep_g[((n * KN + k) * TOBS + tcn) * 2 + 1];
          Ax[k][e] = (f16)(s0 * s_wd0[e] + s1 * s_wd1[e] + s_bd[e]);
        }
      }
      if (tn < TOBS) {
        if (tid < 2) {
          s_scal[tid]     = tabs[(n * TOBS + tn) * 2 + tid];
          s_scal[2 + tid] = trel[(n * TOBS + tn) * 2 + tid];
          s_scal[4 + tid] = tstep[(n * TOBS + tn) * 2 + tid];
        }
        if (tid >= 448) {
          const int e = tid - 448;
          const float a0 = tstep[(n * TOBS + tn) * 2 + 0], a1 = tstep[(n * TOBS + tn) * 2 + 1];
          s_x16[e] = (f16)(a0 * s_wd0[e] + a1 * s_wd1[e] + s_bd[e]);
        }
        if (tid >= 384 && tid < 448) {
          const int a = tid - 384;
          const float r0 = trel[(n * TOBS + tn) * 2 + 0], r1 = trel[(n * TOBS + tn) * 2 + 1];
          s_at[a] = r0 * s_wat0[a] + r1 * s_wat1[a] + s_bat[a];
        }
      }
    }

    if (need_x && tid == 0) {
      const unsigned step = (unsigned)(bn + 1);
      while (ldcoh(otflag) < step)
        __builtin_amdgcn_s_sleep(2);
    }
    __syncthreads();  // D

    // ---- pull partner halves ----
    if (gate_n) {
      const unsigned* Hg = Hglob + (size_t)(par * NT + n) * (KN * 128);
      const int ob = (1 - hb) * 64;
      for (int i = tid; i < KN * 64; i += 512) {
        const int row = i >> 6, c = i & 63;
        const unsigned v = ldcoh(Hg + row * 128 + ob + c);
        *(unsigned*)&Ah[row][(ob + c) * 2] = v;
      }
      #pragma unroll
      for (int rt = 0; rt < 3; ++rt)
        #pragma unroll
        for (int jj = 0; jj < 4; ++jj)
          Ah[rt * 16 + kq * 4 + jj][e_g] = hreg[rt][jj];
    }
    if (do_t && tid >= 448) {
      const int dl = tid - 448;
      const int d = (1 - hb) * 64 + dl;
      const float nh = ldcohf(Tglob + ((size_t)(par * NT + n) * 2 + (1 - hb)) * 64 + dl);
      s_tht[d] = nh;
      s_th16[d] = (f16)nh;
    }
    __syncthreads();  // E

    // ---- Ht (only t >= last29) ----
    if (do_att && tid < EDGE) {
      float h = 0.f;
      for (int k = 0; k < KN; ++k) h += (float)Ah[k][tid] * s_w[k];
      s_Ht[tid] = h;
    }
    if (need_x) bn++;
    if (t >= 29) __syncthreads();  // F
  }
}

extern "C" void kernel_launch(void* const* d_in, const int* in_sizes, int n_in,
                              void* d_out, int out_size, void* d_ws, size_t ws_size,
                              hipStream_t stream) {
  const float* img    = (const float*)d_in[0];
  const float* tabs   = (const float*)d_in[1];
  const float* trel   = (const float*)d_in[2];
  const float* tstep  = (const float*)d_in[3];
  const float* nabs   = (const float*)d_in[4];
  const float* nstep  = (const float*)d_in[6];
  const int*   thist  = (const int*)d_in[7];
  const int*   nhist  = (const int*)d_in[8];
  const float* W_disp = (const float*)d_in[9];
  const float* b_disp = (const float*)d_in[10];
  const float* Wih_t  = (const float*)d_in[11];
  const float* Whh_t  = (const float*)d_in[12];
  const float* bih_t  = (const float*)d_in[13];
  const float* bhh_t  = (const float*)d_in[14];
  const float* Wih_n  = (const float*)d_in[15];
  const float* Whh_n  = (const float*)d_in[16];
  const float* bih_n  = (const float*)d_in[17];
  const float* bhh_n  = (const float*)d_in[18];
  const float* W_att_t = (const float*)d_in[19];
  const float* b_att_t = (const float*)d_in[20];
  const float* W_att_n = (const float*)d_in[21];
  const float* b_att_n = (const float*)d_in[22];
  const float* W_pred  = (const float*)d_in[23];
  const float* b_pred  = (const float*)d_in[24];

  char* ws = (char*)d_ws;
  f16*      Wn      = (f16*)(ws);              // 655360 B
  f16*      Wt      = (f16*)(ws + 655360);     // 196608 B
  float*    bias_n  = (float*)(ws + 851968);
  float*    bias_t  = (float*)(ws + 856064);
  int*      gt_arr  = (int*)(ws + 858112);
  int*      gn_arr  = (int*)(ws + 858304);
  float*    cn_arr  = (float*)(ws + 858496);
  int*      last29p = (int*)(ws + 859648);
  unsigned* flags   = (unsigned*)(ws + 860160);
  unsigned* Hglob   = (unsigned*)(ws + 1048576);  // 3145728 B
  float*    Tglob   = (float*)(ws + 4194304);     // 131072 B

  prep_kernel<<<64, 512, 0, stream>>>(Wih_n, Whh_n, bih_n, bhh_n, Wih_t, Whh_t,
                                      bih_t, bhh_t, thist, nhist, Wn, Wt,
                                      bias_n, bias_t, gt_arr, gn_arr, cn_arr,
                                      last29p, flags);
  model_kernel<<<2 * NT, 512, 0, stream>>>(img, tabs, trel, tstep, nabs, nstep,
                                           thist, nhist, W_disp, b_disp,
                                           W_att_t, b_att_t, W_att_n, b_att_n,
                                           W_pred, b_pred,
                                           Wn, Wt, bias_n, bias_t,
                                           gt_arr, gn_arr, cn_arr, last29p,
                                           flags, Hglob, Tglob,
                                           (float*)d_out);
}